// Round 1
// baseline (525.013 us; speedup 1.0000x reference)
//
#include <hip/hip_runtime.h>
#include <hip/hip_bf16.h>

typedef __attribute__((ext_vector_type(8))) short short8;
typedef __attribute__((ext_vector_type(4))) float f32x4;

#define DEVFN static __device__ __forceinline__

DEVFN float bf2f(unsigned short u) {
    unsigned int i = ((unsigned int)u) << 16;
    float f; __builtin_memcpy(&f, &i, 4); return f;
}
DEVFN unsigned short f2bf(float f) {
    unsigned int i; __builtin_memcpy(&i, &f, 4);
    unsigned int r = i + 0x7fffu + ((i >> 16) & 1u);
    return (unsigned short)(r >> 16);
}

DEVFN void load_lds16(const void* g, void* l) {
    __builtin_amdgcn_global_load_lds(
        (__attribute__((address_space(1))) void*)g,
        (__attribute__((address_space(3))) void*)l, 16, 0, 0);
}

// ---------------- constants ----------------
constexpr int Bsz = 2, T = 2048, C = 1024;
constexpr int NH = 16, NKV = 8, HD = 64;
constexpr int HID = 4096;
constexpr int NTOK = Bsz * T;              // 4096
constexpr size_t MiB = 1024 * 1024;

// workspace offsets (bytes)
constexpr size_t OFF_WQKV = 0;             // bf16 [2048][1024]   4 MiB
constexpr size_t OFF_WOUT = 4 * MiB;       // bf16 [1024][1024]   2 MiB
constexpr size_t OFF_WGATE = 6 * MiB;      // bf16 [4096][1024]   8 MiB
constexpr size_t OFF_WUP = 14 * MiB;       // bf16 [4096][1024]   8 MiB
constexpr size_t OFF_WDOWN = 22 * MiB;     // bf16 [1024][4096]   8 MiB
constexpr size_t OFF_XN1 = 30 * MiB;       // bf16 [4096][1024]   8 MiB
constexpr size_t OFF_QKVF = 38 * MiB;      // f32  [4096][2048]  32 MiB
constexpr size_t OFF_QB = 70 * MiB;        // bf16 [2][16][2048][64] 8 MiB
constexpr size_t OFF_KB = 78 * MiB;        // bf16 [2][8][2048][64]  4 MiB
constexpr size_t OFF_VT = 82 * MiB;        // bf16 [2][8][64][2048]  4 MiB
constexpr size_t OFF_CTX = 86 * MiB;       // bf16 [4096][1024]   8 MiB
constexpr size_t OFF_X2 = 94 * MiB;        // f32  [4096][1024]  16 MiB
constexpr size_t OFF_XN2 = 110 * MiB;      // bf16 [4096][1024]   8 MiB
constexpr size_t OFF_G = 118 * MiB;        // bf16 [4096][4096]  32 MiB (h aliases g)
// total 150 MiB

// ---------------- weight cast + transpose: in[K][N] f32 -> out[N][K] bf16 ----------------
__global__ __launch_bounds__(256) void transpose_cast(const float* __restrict__ in,
                                                      unsigned short* __restrict__ out,
                                                      int K, int N) {
    __shared__ float t[32][33];
    int n0 = blockIdx.x * 32, k0 = blockIdx.y * 32;
    int tx = threadIdx.x & 31, ty = threadIdx.x >> 5;  // ty in [0,8)
#pragma unroll
    for (int i = 0; i < 4; i++)
        t[ty + 8 * i][tx] = in[(size_t)(k0 + ty + 8 * i) * N + n0 + tx];
    __syncthreads();
#pragma unroll
    for (int i = 0; i < 4; i++)
        out[(size_t)(n0 + ty + 8 * i) * K + k0 + tx] = f2bf(t[tx][ty + 8 * i]);
}

// ---------------- RMS norm: f32 [rows][1024] -> bf16, *(1+scale) ----------------
__global__ __launch_bounds__(256) void rms_kernel(const float* __restrict__ in,
                                                  const float* __restrict__ scale,
                                                  unsigned short* __restrict__ out) {
    __shared__ float red[4];
    int row = blockIdx.x, tid = threadIdx.x;
    const float4 v = *(const float4*)&in[(size_t)row * 1024 + tid * 4];
    float ss = v.x * v.x + v.y * v.y + v.z * v.z + v.w * v.w;
#pragma unroll
    for (int m = 32; m; m >>= 1) ss += __shfl_xor(ss, m, 64);
    if ((tid & 63) == 0) red[tid >> 6] = ss;
    __syncthreads();
    float tot = red[0] + red[1] + red[2] + red[3];
    float inv = rsqrtf(tot * (1.f / 1024.f) + 1e-6f);
    const float4 sc = *(const float4*)&scale[tid * 4];
    size_t o = (size_t)row * 1024 + tid * 4;
    out[o + 0] = f2bf(v.x * inv * (1.f + sc.x));
    out[o + 1] = f2bf(v.y * inv * (1.f + sc.y));
    out[o + 2] = f2bf(v.z * inv * (1.f + sc.z));
    out[o + 3] = f2bf(v.w * inv * (1.f + sc.w));
}

// ---------------- GEMM: C[M][N] = A[M][K] @ Bt[N][K]^T, bf16 in, fp32 acc ----------------
// EPI: 0 = fp32 store; 1 = fp32 store + residual(aux fp32); 2 = bf16 silu; 3 = bf16 * aux(bf16)
template <int EPI>
__global__ __launch_bounds__(256) void gemm128(const unsigned short* __restrict__ A,
                                               const unsigned short* __restrict__ Bt,
                                               void* __restrict__ Cp,
                                               const void* __restrict__ aux,
                                               int M, int N, int K) {
    __shared__ __align__(16) unsigned short As[128 * 32];
    __shared__ __align__(16) unsigned short Bs[128 * 32];
    const int tid = threadIdx.x;
    const int lane = tid & 63, w = tid >> 6;
    const int quad = lane >> 4, l15 = lane & 15;
    const int wr = w >> 1, wc = w & 1;
    const int m0 = blockIdx.y * 128, n0 = blockIdx.x * 128;

    f32x4 acc[4][4];
#pragma unroll
    for (int i = 0; i < 4; i++)
#pragma unroll
        for (int j = 0; j < 4; j++) acc[i][j] = f32x4{0.f, 0.f, 0.f, 0.f};

    const int stRow = (w << 4) + (lane >> 2);
    const int stCol = (lane & 3) << 3;

    for (int kk = 0; kk < K; kk += 32) {
#pragma unroll
        for (int i = 0; i < 2; i++) {
            load_lds16(A + (size_t)(m0 + (i << 6) + stRow) * K + kk + stCol,
                       &As[((i << 6) + (w << 4)) * 32]);
            load_lds16(Bt + (size_t)(n0 + (i << 6) + stRow) * K + kk + stCol,
                       &Bs[((i << 6) + (w << 4)) * 32]);
        }
        __syncthreads();
        short8 a[4], b[4];
#pragma unroll
        for (int mi = 0; mi < 4; mi++)
            a[mi] = *(const short8*)&As[(wr * 64 + mi * 16 + l15) * 32 + quad * 8];
#pragma unroll
        for (int ni = 0; ni < 4; ni++)
            b[ni] = *(const short8*)&Bs[(wc * 64 + ni * 16 + l15) * 32 + quad * 8];
#pragma unroll
        for (int mi = 0; mi < 4; mi++)
#pragma unroll
            for (int ni = 0; ni < 4; ni++)
                acc[mi][ni] = __builtin_amdgcn_mfma_f32_16x16x32_bf16(a[mi], b[ni], acc[mi][ni], 0, 0, 0);
        __syncthreads();
    }
#pragma unroll
    for (int mi = 0; mi < 4; mi++) {
#pragma unroll
        for (int ni = 0; ni < 4; ni++) {
#pragma unroll
            for (int r = 0; r < 4; r++) {
                int row = m0 + wr * 64 + mi * 16 + quad * 4 + r;
                int col = n0 + wc * 64 + ni * 16 + l15;
                size_t idx = (size_t)row * N + col;
                float v = acc[mi][ni][r];
                if constexpr (EPI == 0) {
                    ((float*)Cp)[idx] = v;
                } else if constexpr (EPI == 1) {
                    ((float*)Cp)[idx] = v + ((const float*)aux)[idx];
                } else if constexpr (EPI == 2) {
                    float s = v / (1.f + __expf(-v));
                    ((unsigned short*)Cp)[idx] = f2bf(s);
                } else {
                    float g = bf2f(((const unsigned short*)aux)[idx]);
                    ((unsigned short*)Cp)[idx] = f2bf(v * g);
                }
            }
        }
    }
}

// ---------------- RoPE scatter: qkvf f32 [tok][2048] -> qb/kb bf16 head-major ----------------
__global__ __launch_bounds__(256) void rope_kernel(const float* __restrict__ qkvf,
                                                   unsigned short* __restrict__ qb,
                                                   unsigned short* __restrict__ kb) {
    __shared__ float sv[32], cv[32];
    int tok = blockIdx.x;
    int b = tok >> 11, t = tok & 2047;
    int tid = threadIdx.x;
    if (tid < 32) {
        float fr = (float)tid * (1.f / 32.f);
        float freq = powf(1e6f, -fr);
        float a = (float)t * freq;
        sv[tid] = sinf(a);
        cv[tid] = cosf(a);
    }
    __syncthreads();
    const float* rowp = qkvf + (size_t)tok * 2048;
#pragma unroll
    for (int e = tid; e < 1536; e += 256) {
        int u = e >> 6, d = e & 63;
        int col = (u < 16) ? (u * 64 + d) : (1024 + (u - 16) * 64 + d);
        int pcol = (d < 32) ? col + 32 : col - 32;
        float sgn = (d < 32) ? -1.f : 1.f;
        float o = rowp[col] * cv[d & 31] + sgn * rowp[pcol] * sv[d & 31];
        if (u < 16)
            qb[((size_t)(b * 16 + u) * 2048 + t) * 64 + d] = f2bf(o);
        else
            kb[((size_t)(b * 8 + (u - 16)) * 2048 + t) * 64 + d] = f2bf(o);
    }
}

// ---------------- V transpose: qkvf v-cols -> vt bf16 [b][h][64 d][2048 t] ----------------
__global__ __launch_bounds__(256) void vtrans_kernel(const float* __restrict__ qkvf,
                                                     unsigned short* __restrict__ vt) {
    __shared__ float tile[64][65];
    int t0 = blockIdx.x * 64, h = blockIdx.y, b = blockIdx.z;
    int tid = threadIdx.x;
    int d = tid & 63, tr = tid >> 6;
#pragma unroll
    for (int i = 0; i < 16; i++) {
        int t = tr + i * 4;
        tile[t][d] = qkvf[(size_t)(b * 2048 + t0 + t) * 2048 + 1536 + h * 64 + d];
    }
    __syncthreads();
    int tt = tid & 63, dr = tid >> 6;
#pragma unroll
    for (int i = 0; i < 16; i++) {
        int dd = dr + i * 4;
        vt[((size_t)(b * 8 + h) * 64 + dd) * 2048 + t0 + tt] = f2bf(tile[tt][dd]);
    }
}

// ---------------- flash attention, sliding window, soft cap ----------------
__global__ __launch_bounds__(256) void attn_kernel(const unsigned short* __restrict__ qb,
                                                   const unsigned short* __restrict__ kb,
                                                   const unsigned short* __restrict__ vt,
                                                   unsigned short* __restrict__ ctx) {
    __shared__ __align__(16) unsigned short P[4][16 * 32];
    const int tid = threadIdx.x, lane = tid & 63, w = tid >> 6;
    const int quad = lane >> 4, l15 = lane & 15;
    const int qt = blockIdx.x, H = blockIdx.y, b = blockIdx.z;
    const int hkv = H & 7;
    const int qw = qt * 64 + w * 16;

    const unsigned short* qbase = qb + ((size_t)(b * 16 + H) * 2048 + qw) * 64;
    short8 aq0 = *(const short8*)(qbase + (size_t)l15 * 64 + quad * 8);
    short8 aq1 = *(const short8*)(qbase + (size_t)l15 * 64 + 32 + quad * 8);

    const unsigned short* kbase = kb + (size_t)(b * 8 + hkv) * 2048 * 64;
    const unsigned short* vbase = vt + (size_t)(b * 8 + hkv) * 64 * 2048;

    f32x4 O[4];
#pragma unroll
    for (int i = 0; i < 4; i++) O[i] = f32x4{0.f, 0.f, 0.f, 0.f};
    float mrow[4], lrow[4];
#pragma unroll
    for (int r = 0; r < 4; r++) { mrow[r] = -1e30f; lrow[r] = 0.f; }

    int kstart = qw - 511;
    if (kstart < 0) kstart = 0;
    kstart &= ~31;
    unsigned short* Pw = P[w];

    for (int k0 = kstart; k0 <= qw + 15; k0 += 32) {
        f32x4 S[2];
#pragma unroll
        for (int c = 0; c < 2; c++) {
            const unsigned short* kp = kbase + (size_t)(k0 + c * 16 + l15) * 64 + quad * 8;
            short8 kf0 = *(const short8*)kp;
            short8 kf1 = *(const short8*)(kp + 32);
            f32x4 s = __builtin_amdgcn_mfma_f32_16x16x32_bf16(aq0, kf0, f32x4{0.f, 0.f, 0.f, 0.f}, 0, 0, 0);
            s = __builtin_amdgcn_mfma_f32_16x16x32_bf16(aq1, kf1, s, 0, 0, 0);
            S[c] = s;
        }
        float y[2][4];
#pragma unroll
        for (int c = 0; c < 2; c++)
#pragma unroll
            for (int r = 0; r < 4; r++) {
                int i = qw + quad * 4 + r;
                int j = k0 + c * 16 + l15;
                float x = S[c][r] * 0.125f;
                float tt = x * 0.02f;
                tt = fminf(8.f, fmaxf(-8.f, tt));
                float e = __expf(2.f * tt);
                float yv = 50.f * (e - 1.f) / (e + 1.f);
                y[c][r] = (j <= i && (i - j) < 512) ? yv : -__builtin_inff();
            }
        float p[2][4], alpha[4];
#pragma unroll
        for (int r = 0; r < 4; r++) {
            float v = fmaxf(y[0][r], y[1][r]);
#pragma unroll
            for (int mm = 8; mm; mm >>= 1) v = fmaxf(v, __shfl_xor(v, mm, 16));
            float mnew = fmaxf(mrow[r], v);
            alpha[r] = __expf(mrow[r] - mnew);
            float p0 = __expf(y[0][r] - mnew);
            float p1 = __expf(y[1][r] - mnew);
            p[0][r] = p0; p[1][r] = p1;
            float rs = p0 + p1;
#pragma unroll
            for (int mm = 8; mm; mm >>= 1) rs += __shfl_xor(rs, mm, 16);
            lrow[r] = lrow[r] * alpha[r] + rs;
            mrow[r] = mnew;
        }
#pragma unroll
        for (int c = 0; c < 2; c++)
#pragma unroll
            for (int r = 0; r < 4; r++)
                Pw[(quad * 4 + r) * 32 + c * 16 + l15] = f2bf(p[c][r]);
        asm volatile("s_waitcnt lgkmcnt(0)" ::: "memory");
        short8 pf = *(const short8*)&Pw[l15 * 32 + quad * 8];
#pragma unroll
        for (int ni = 0; ni < 4; ni++) {
            short8 vf = *(const short8*)(vbase + (size_t)(ni * 16 + l15) * 2048 + k0 + quad * 8);
            f32x4 o = O[ni];
#pragma unroll
            for (int r = 0; r < 4; r++) o[r] *= alpha[r];
            O[ni] = __builtin_amdgcn_mfma_f32_16x16x32_bf16(pf, vf, o, 0, 0, 0);
        }
        asm volatile("s_waitcnt lgkmcnt(0)" ::: "memory");
    }
#pragma unroll
    for (int r = 0; r < 4; r++) {
        float inv = 1.f / lrow[r];
        int i = qw + quad * 4 + r;
        size_t tok = (size_t)b * 2048 + i;
#pragma unroll
        for (int ni = 0; ni < 4; ni++)
            ctx[tok * 1024 + H * 64 + ni * 16 + l15] = f2bf(O[ni][r] * inv);
    }
}

// ---------------- kurtosis ----------------
__global__ void kurt_init(float* dst, const float* ksum) { dst[0] = ksum[0]; }

__global__ __launch_bounds__(256) void kurt_kernel(const float* __restrict__ xf,
                                                   float* __restrict__ dst) {
    __shared__ float red[4], r2[4], r4[4];
    int row = blockIdx.x, tid = threadIdx.x;
    float4 v = *(const float4*)&xf[(size_t)row * 1024 + tid * 4];
    float s = v.x + v.y + v.z + v.w;
#pragma unroll
    for (int m = 32; m; m >>= 1) s += __shfl_xor(s, m, 64);
    if ((tid & 63) == 0) red[tid >> 6] = s;
    __syncthreads();
    float mean = (red[0] + red[1] + red[2] + red[3]) * (1.f / 1024.f);
    float cx = v.x - mean, cy = v.y - mean, cz = v.z - mean, cw = v.w - mean;
    float x2 = cx * cx, y2 = cy * cy, z2 = cz * cz, w2 = cw * cw;
    float c2 = x2 + y2 + z2 + w2;
    float c4 = x2 * x2 + y2 * y2 + z2 * z2 + w2 * w2;
#pragma unroll
    for (int m = 32; m; m >>= 1) {
        c2 += __shfl_xor(c2, m, 64);
        c4 += __shfl_xor(c4, m, 64);
    }
    if ((tid & 63) == 0) { r2[tid >> 6] = c2; r4[tid >> 6] = c4; }
    __syncthreads();
    if (tid == 0) {
        float m2 = (r2[0] + r2[1] + r2[2] + r2[3]) * (1.f / 1024.f);
        float m4 = (r4[0] + r4[1] + r4[2] + r4[3]) * (1.f / 1024.f);
        float kurt = m4 / (m2 * m2 + 1e-6f) - 3.f;
        if (kurt > 0.f) atomicAdd(dst, kurt);
    }
}

// ---------------- launch ----------------
extern "C" void kernel_launch(void* const* d_in, const int* in_sizes, int n_in,
                              void* d_out, int out_size, void* d_ws, size_t ws_size,
                              hipStream_t stream) {
    const float* x = (const float*)d_in[0];
    const float* ksum = (const float*)d_in[1];
    const float* rms1_scale = (const float*)d_in[2];
    const float* q_kernel = (const float*)d_in[3];
    const float* k_kernel = (const float*)d_in[4];
    const float* v_kernel = (const float*)d_in[5];
    const float* out_kernel = (const float*)d_in[6];
    const float* rms2_scale = (const float*)d_in[7];
    const float* gate_kernel = (const float*)d_in[8];
    const float* up_kernel = (const float*)d_in[9];
    const float* down_kernel = (const float*)d_in[10];

    char* ws = (char*)d_ws;
    unsigned short* wqkv = (unsigned short*)(ws + OFF_WQKV);
    unsigned short* wout = (unsigned short*)(ws + OFF_WOUT);
    unsigned short* wgate = (unsigned short*)(ws + OFF_WGATE);
    unsigned short* wup = (unsigned short*)(ws + OFF_WUP);
    unsigned short* wdown = (unsigned short*)(ws + OFF_WDOWN);
    unsigned short* xn1 = (unsigned short*)(ws + OFF_XN1);
    float* qkvf = (float*)(ws + OFF_QKVF);
    unsigned short* qb = (unsigned short*)(ws + OFF_QB);
    unsigned short* kb = (unsigned short*)(ws + OFF_KB);
    unsigned short* vtb = (unsigned short*)(ws + OFF_VT);
    unsigned short* ctx = (unsigned short*)(ws + OFF_CTX);
    float* x2 = (float*)(ws + OFF_X2);
    unsigned short* xn2 = (unsigned short*)(ws + OFF_XN2);
    unsigned short* g = (unsigned short*)(ws + OFF_G);
    float* outx = (float*)d_out;
    float* outk = outx + (size_t)NTOK * C;  // kurtosis scalar slot

    // weight cast + transpose (W[K][N] -> Wt[N][K] bf16)
    transpose_cast<<<dim3(1024 / 32, 1024 / 32), 256, 0, stream>>>(q_kernel, wqkv, 1024, 1024);
    transpose_cast<<<dim3(512 / 32, 1024 / 32), 256, 0, stream>>>(k_kernel, wqkv + (size_t)1024 * 1024, 1024, 512);
    transpose_cast<<<dim3(512 / 32, 1024 / 32), 256, 0, stream>>>(v_kernel, wqkv + (size_t)1536 * 1024, 1024, 512);
    transpose_cast<<<dim3(1024 / 32, 1024 / 32), 256, 0, stream>>>(out_kernel, wout, 1024, 1024);
    transpose_cast<<<dim3(4096 / 32, 1024 / 32), 256, 0, stream>>>(gate_kernel, wgate, 1024, 4096);
    transpose_cast<<<dim3(4096 / 32, 1024 / 32), 256, 0, stream>>>(up_kernel, wup, 1024, 4096);
    transpose_cast<<<dim3(1024 / 32, 4096 / 32), 256, 0, stream>>>(down_kernel, wdown, 4096, 1024);

    // attention input norm
    rms_kernel<<<NTOK, 256, 0, stream>>>(x, rms1_scale, xn1);

    // QKV projection: [4096][1024] @ [1024][2048] -> fp32
    gemm128<0><<<dim3(2048 / 128, NTOK / 128), 256, 0, stream>>>(xn1, wqkv, qkvf, nullptr, NTOK, 2048, 1024);

    // RoPE + layout scatter, V transpose
    rope_kernel<<<NTOK, 256, 0, stream>>>(qkvf, qb, kb);
    vtrans_kernel<<<dim3(T / 64, NKV, Bsz), 256, 0, stream>>>(qkvf, vtb);

    // attention
    attn_kernel<<<dim3(T / 64, NH, Bsz), 256, 0, stream>>>(qb, kb, vtb, ctx);

    // out projection + residual -> x2
    gemm128<1><<<dim3(1024 / 128, NTOK / 128), 256, 0, stream>>>(ctx, wout, x2, x, NTOK, 1024, 1024);

    // MLP
    rms_kernel<<<NTOK, 256, 0, stream>>>(x2, rms2_scale, xn2);
    gemm128<2><<<dim3(4096 / 128, NTOK / 128), 256, 0, stream>>>(xn2, wgate, g, nullptr, NTOK, 4096, 1024);
    gemm128<3><<<dim3(4096 / 128, NTOK / 128), 256, 0, stream>>>(xn2, wup, g, g, NTOK, 4096, 1024);
    gemm128<1><<<dim3(1024 / 128, NTOK / 128), 256, 0, stream>>>(g, wdown, outx, x2, NTOK, 1024, 4096);

    // kurtosis
    kurt_init<<<1, 1, 0, stream>>>(outk, ksum);
    kurt_kernel<<<NTOK, 256, 0, stream>>>(outx, outk);

    (void)in_sizes; (void)n_in; (void)out_size; (void)ws_size;
}

// Round 2
// 470.168 us; speedup vs baseline: 1.1167x; 1.1167x over previous
//
#include <hip/hip_runtime.h>
#include <hip/hip_bf16.h>

typedef __attribute__((ext_vector_type(8))) short short8;
typedef __attribute__((ext_vector_type(4))) float f32x4;

#define DEVFN static __device__ __forceinline__

DEVFN float bf2f(unsigned short u) {
    unsigned int i = ((unsigned int)u) << 16;
    float f; __builtin_memcpy(&f, &i, 4); return f;
}
DEVFN unsigned short f2bf(float f) {
    unsigned int i; __builtin_memcpy(&i, &f, 4);
    unsigned int r = i + 0x7fffu + ((i >> 16) & 1u);
    return (unsigned short)(r >> 16);
}

DEVFN void load_lds16(const void* g, void* l) {
    __builtin_amdgcn_global_load_lds(
        (__attribute__((address_space(1))) void*)g,
        (__attribute__((address_space(3))) void*)l, 16, 0, 0);
}

// ---------------- constants ----------------
constexpr int Bsz = 2, T = 2048, C = 1024;
constexpr int NH = 16, NKV = 8, HD = 64;
constexpr int HID = 4096;
constexpr int NTOK = Bsz * T;              // 4096
constexpr size_t MiB = 1024 * 1024;

// workspace offsets (bytes)
constexpr size_t OFF_WQKV = 0;             // bf16 [2048][1024]   4 MiB
constexpr size_t OFF_WOUT = 4 * MiB;       // bf16 [1024][1024]   2 MiB
constexpr size_t OFF_WGATE = 6 * MiB;      // bf16 [4096][1024]   8 MiB
constexpr size_t OFF_WUP = 14 * MiB;       // bf16 [4096][1024]   8 MiB
constexpr size_t OFF_WDOWN = 22 * MiB;     // bf16 [1024][4096]   8 MiB
constexpr size_t OFF_XN1 = 30 * MiB;       // bf16 [4096][1024]   8 MiB
constexpr size_t OFF_QKVB = 38 * MiB;      // bf16 [4096][2048]  16 MiB (dead after rope/vtrans)
constexpr size_t OFF_P2 = 38 * MiB;        // f32  2x[4096][1024] 32 MiB (out-proj partials; reuses QKVB)
constexpr size_t OFF_P4 = 30 * MiB;        // f32  4x[4096][1024] 64 MiB (down partials; reuses 30..94)
constexpr size_t OFF_QB = 70 * MiB;        // bf16 [2][16][2048][64] 8 MiB
constexpr size_t OFF_KB = 78 * MiB;        // bf16 [2][8][2048][64]  4 MiB
constexpr size_t OFF_VT = 82 * MiB;        // bf16 [2][8][64][2048]  4 MiB
constexpr size_t OFF_CTX = 86 * MiB;       // bf16 [4096][1024]   8 MiB
constexpr size_t OFF_X2 = 94 * MiB;        // f32  [4096][1024]  16 MiB
constexpr size_t OFF_XN2 = 110 * MiB;      // bf16 [4096][1024]   8 MiB
constexpr size_t OFF_G = 118 * MiB;        // bf16 [4096][4096]  32 MiB
// total 150 MiB

// ---------------- weight cast + transpose: in[K][N] f32 -> out[N][K] bf16 ----------------
__global__ __launch_bounds__(256) void transpose_cast(const float* __restrict__ in,
                                                      unsigned short* __restrict__ out,
                                                      int K, int N) {
    __shared__ float t[32][33];
    int n0 = blockIdx.x * 32, k0 = blockIdx.y * 32;
    int tx = threadIdx.x & 31, ty = threadIdx.x >> 5;
#pragma unroll
    for (int i = 0; i < 4; i++)
        t[ty + 8 * i][tx] = in[(size_t)(k0 + ty + 8 * i) * N + n0 + tx];
    __syncthreads();
#pragma unroll
    for (int i = 0; i < 4; i++)
        out[(size_t)(n0 + ty + 8 * i) * K + k0 + tx] = f2bf(t[tx][ty + 8 * i]);
}

// ---------------- RMS norm: f32 [rows][1024] -> bf16, *(1+scale) ----------------
__global__ __launch_bounds__(256) void rms_kernel(const float* __restrict__ in,
                                                  const float* __restrict__ scale,
                                                  unsigned short* __restrict__ out) {
    __shared__ float red[4];
    int row = blockIdx.x, tid = threadIdx.x;
    const float4 v = *(const float4*)&in[(size_t)row * 1024 + tid * 4];
    float ss = v.x * v.x + v.y * v.y + v.z * v.z + v.w * v.w;
#pragma unroll
    for (int m = 32; m; m >>= 1) ss += __shfl_xor(ss, m, 64);
    if ((tid & 63) == 0) red[tid >> 6] = ss;
    __syncthreads();
    float tot = red[0] + red[1] + red[2] + red[3];
    float inv = rsqrtf(tot * (1.f / 1024.f) + 1e-6f);
    const float4 sc = *(const float4*)&scale[tid * 4];
    size_t o = (size_t)row * 1024 + tid * 4;
    out[o + 0] = f2bf(v.x * inv * (1.f + sc.x));
    out[o + 1] = f2bf(v.y * inv * (1.f + sc.y));
    out[o + 2] = f2bf(v.z * inv * (1.f + sc.z));
    out[o + 3] = f2bf(v.w * inv * (1.f + sc.w));
}

// ---------------- GEMM: C[M][N](+z) = A[M][K] @ Bt[N][K]^T, bf16 in, fp32 acc ----------------
// EPI: 0 = fp32 store; 4 = bf16 store. blockIdx.z selects K-slice (zA/zB elem offsets, zC out offset).
template <int EPI>
__global__ __launch_bounds__(256) void gemm128(const unsigned short* __restrict__ A,
                                               const unsigned short* __restrict__ Bt,
                                               void* __restrict__ Cp,
                                               int N, int K, int lda, int ldb,
                                               size_t zA, size_t zB, size_t zC) {
    __shared__ __align__(16) unsigned short As[128 * 32];
    __shared__ __align__(16) unsigned short Bs[128 * 32];
    A += (size_t)blockIdx.z * zA;
    Bt += (size_t)blockIdx.z * zB;
    const int tid = threadIdx.x;
    const int lane = tid & 63, w = tid >> 6;
    const int quad = lane >> 4, l15 = lane & 15;
    const int wr = w >> 1, wc = w & 1;
    const int m0 = blockIdx.y * 128, n0 = blockIdx.x * 128;

    f32x4 acc[4][4];
#pragma unroll
    for (int i = 0; i < 4; i++)
#pragma unroll
        for (int j = 0; j < 4; j++) acc[i][j] = f32x4{0.f, 0.f, 0.f, 0.f};

    const int stRow = (w << 4) + (lane >> 2);
    const int stCol = (lane & 3) << 3;

    for (int kk = 0; kk < K; kk += 32) {
#pragma unroll
        for (int i = 0; i < 2; i++) {
            load_lds16(A + (size_t)(m0 + (i << 6) + stRow) * lda + kk + stCol,
                       &As[((i << 6) + (w << 4)) * 32]);
            load_lds16(Bt + (size_t)(n0 + (i << 6) + stRow) * ldb + kk + stCol,
                       &Bs[((i << 6) + (w << 4)) * 32]);
        }
        __syncthreads();
        short8 a[4], b[4];
#pragma unroll
        for (int mi = 0; mi < 4; mi++)
            a[mi] = *(const short8*)&As[(wr * 64 + mi * 16 + l15) * 32 + quad * 8];
#pragma unroll
        for (int ni = 0; ni < 4; ni++)
            b[ni] = *(const short8*)&Bs[(wc * 64 + ni * 16 + l15) * 32 + quad * 8];
#pragma unroll
        for (int mi = 0; mi < 4; mi++)
#pragma unroll
            for (int ni = 0; ni < 4; ni++)
                acc[mi][ni] = __builtin_amdgcn_mfma_f32_16x16x32_bf16(a[mi], b[ni], acc[mi][ni], 0, 0, 0);
        __syncthreads();
    }
#pragma unroll
    for (int mi = 0; mi < 4; mi++) {
#pragma unroll
        for (int ni = 0; ni < 4; ni++) {
#pragma unroll
            for (int r = 0; r < 4; r++) {
                int row = m0 + wr * 64 + mi * 16 + quad * 4 + r;
                int col = n0 + wc * 64 + ni * 16 + l15;
                size_t idx = (size_t)blockIdx.z * zC + (size_t)row * N + col;
                float v = acc[mi][ni][r];
                if constexpr (EPI == 0) {
                    ((float*)Cp)[idx] = v;
                } else {
                    ((unsigned short*)Cp)[idx] = f2bf(v);
                }
            }
        }
    }
}

// ---------------- fused gate+up GEMM: 128x64 tile of BOTH gate and up, epilogue silu(g)*u ----------------
__global__ __launch_bounds__(256) void gateup_kernel(const unsigned short* __restrict__ A,
                                                     const unsigned short* __restrict__ Bg,
                                                     const unsigned short* __restrict__ Bu,
                                                     unsigned short* __restrict__ out) {
    __shared__ __align__(16) unsigned short As[128 * 32];
    __shared__ __align__(16) unsigned short Gs[64 * 32];
    __shared__ __align__(16) unsigned short Us[64 * 32];
    const int tid = threadIdx.x;
    const int lane = tid & 63, w = tid >> 6;
    const int quad = lane >> 4, l15 = lane & 15;
    const int wr = w >> 1, wc = w & 1;
    const int m0 = blockIdx.y * 128, n0 = blockIdx.x * 64;

    f32x4 aG[4][2], aU[4][2];
#pragma unroll
    for (int i = 0; i < 4; i++)
#pragma unroll
        for (int j = 0; j < 2; j++) { aG[i][j] = f32x4{0.f, 0.f, 0.f, 0.f}; aU[i][j] = f32x4{0.f, 0.f, 0.f, 0.f}; }

    const int stRow = (w << 4) + (lane >> 2);   // 0..63
    const int stCol = (lane & 3) << 3;

    for (int kk = 0; kk < 1024; kk += 32) {
#pragma unroll
        for (int i = 0; i < 2; i++)
            load_lds16(A + (size_t)(m0 + (i << 6) + stRow) * 1024 + kk + stCol,
                       &As[((i << 6) + (w << 4)) * 32]);
        load_lds16(Bg + (size_t)(n0 + stRow) * 1024 + kk + stCol, &Gs[(w << 4) * 32]);
        load_lds16(Bu + (size_t)(n0 + stRow) * 1024 + kk + stCol, &Us[(w << 4) * 32]);
        __syncthreads();
        short8 a[4], bg[2], bu[2];
#pragma unroll
        for (int mi = 0; mi < 4; mi++)
            a[mi] = *(const short8*)&As[(wr * 64 + mi * 16 + l15) * 32 + quad * 8];
#pragma unroll
        for (int ni = 0; ni < 2; ni++) {
            bg[ni] = *(const short8*)&Gs[(wc * 32 + ni * 16 + l15) * 32 + quad * 8];
            bu[ni] = *(const short8*)&Us[(wc * 32 + ni * 16 + l15) * 32 + quad * 8];
        }
#pragma unroll
        for (int mi = 0; mi < 4; mi++)
#pragma unroll
            for (int ni = 0; ni < 2; ni++) {
                aG[mi][ni] = __builtin_amdgcn_mfma_f32_16x16x32_bf16(a[mi], bg[ni], aG[mi][ni], 0, 0, 0);
                aU[mi][ni] = __builtin_amdgcn_mfma_f32_16x16x32_bf16(a[mi], bu[ni], aU[mi][ni], 0, 0, 0);
            }
        __syncthreads();
    }
#pragma unroll
    for (int mi = 0; mi < 4; mi++)
#pragma unroll
        for (int ni = 0; ni < 2; ni++)
#pragma unroll
            for (int r = 0; r < 4; r++) {
                int row = m0 + wr * 64 + mi * 16 + quad * 4 + r;
                int col = n0 + wc * 32 + ni * 16 + l15;
                float vg = aG[mi][ni][r], vu = aU[mi][ni][r];
                float s = vg / (1.f + __expf(-vg));
                out[(size_t)row * 4096 + col] = f2bf(s * vu);
            }
}

// ---------------- out-proj reduce: x2 = p0+p1+x; xn2 = rms(x2)*(1+scale) ----------------
__global__ __launch_bounds__(256) void reduce_out(const float* __restrict__ p,
                                                  const float* __restrict__ x,
                                                  const float* __restrict__ scale,
                                                  float* __restrict__ x2,
                                                  unsigned short* __restrict__ xn2) {
    __shared__ float red[4];
    int row = blockIdx.x, tid = threadIdx.x;
    size_t base = (size_t)row * 1024 + tid * 4;
    const float4 a = *(const float4*)&p[base];
    const float4 b = *(const float4*)&p[base + (size_t)NTOK * 1024];
    const float4 xr = *(const float4*)&x[base];
    float4 v = {a.x + b.x + xr.x, a.y + b.y + xr.y, a.z + b.z + xr.z, a.w + b.w + xr.w};
    *(float4*)&x2[base] = v;
    float ss = v.x * v.x + v.y * v.y + v.z * v.z + v.w * v.w;
#pragma unroll
    for (int m = 32; m; m >>= 1) ss += __shfl_xor(ss, m, 64);
    if ((tid & 63) == 0) red[tid >> 6] = ss;
    __syncthreads();
    float tot = red[0] + red[1] + red[2] + red[3];
    float inv = rsqrtf(tot * (1.f / 1024.f) + 1e-6f);
    const float4 sc = *(const float4*)&scale[tid * 4];
    xn2[base + 0] = f2bf(v.x * inv * (1.f + sc.x));
    xn2[base + 1] = f2bf(v.y * inv * (1.f + sc.y));
    xn2[base + 2] = f2bf(v.z * inv * (1.f + sc.z));
    xn2[base + 3] = f2bf(v.w * inv * (1.f + sc.w));
}

// ---------------- down reduce: out = p0..p3 + x2, fused kurtosis ----------------
__global__ __launch_bounds__(256) void reduce_down(const float* __restrict__ p,
                                                   const float* __restrict__ x2,
                                                   float* __restrict__ outx,
                                                   float* __restrict__ outk) {
    __shared__ float red[4], r2[4], r4[4];
    int row = blockIdx.x, tid = threadIdx.x;
    size_t base = (size_t)row * 1024 + tid * 4;
    const size_t Z = (size_t)NTOK * 1024;
    float4 v = *(const float4*)&p[base];
    const float4 b = *(const float4*)&p[base + Z];
    const float4 c = *(const float4*)&p[base + 2 * Z];
    const float4 d = *(const float4*)&p[base + 3 * Z];
    const float4 xr = *(const float4*)&x2[base];
    v.x += b.x + c.x + d.x + xr.x;
    v.y += b.y + c.y + d.y + xr.y;
    v.z += b.z + c.z + d.z + xr.z;
    v.w += b.w + c.w + d.w + xr.w;
    *(float4*)&outx[base] = v;
    float s = v.x + v.y + v.z + v.w;
#pragma unroll
    for (int m = 32; m; m >>= 1) s += __shfl_xor(s, m, 64);
    if ((tid & 63) == 0) red[tid >> 6] = s;
    __syncthreads();
    float mean = (red[0] + red[1] + red[2] + red[3]) * (1.f / 1024.f);
    float cx = v.x - mean, cy = v.y - mean, cz = v.z - mean, cw = v.w - mean;
    float x2v = cx * cx, y2 = cy * cy, z2 = cz * cz, w2 = cw * cw;
    float c2 = x2v + y2 + z2 + w2;
    float c4 = x2v * x2v + y2 * y2 + z2 * z2 + w2 * w2;
#pragma unroll
    for (int m = 32; m; m >>= 1) {
        c2 += __shfl_xor(c2, m, 64);
        c4 += __shfl_xor(c4, m, 64);
    }
    if ((tid & 63) == 0) { r2[tid >> 6] = c2; r4[tid >> 6] = c4; }
    __syncthreads();
    if (tid == 0) {
        float m2 = (r2[0] + r2[1] + r2[2] + r2[3]) * (1.f / 1024.f);
        float m4 = (r4[0] + r4[1] + r4[2] + r4[3]) * (1.f / 1024.f);
        float kurt = m4 / (m2 * m2 + 1e-6f) - 3.f;
        if (kurt > 0.f) atomicAdd(outk, kurt);
    }
}

// ---------------- RoPE scatter: qkvb bf16 [tok][2048] -> qb/kb bf16 head-major ----------------
__global__ __launch_bounds__(256) void rope_kernel(const unsigned short* __restrict__ qkvb,
                                                   unsigned short* __restrict__ qb,
                                                   unsigned short* __restrict__ kb) {
    __shared__ float sv[32], cv[32];
    int tok = blockIdx.x;
    int b = tok >> 11, t = tok & 2047;
    int tid = threadIdx.x;
    if (tid < 32) {
        float fr = (float)tid * (1.f / 32.f);
        float freq = powf(1e6f, -fr);
        float a = (float)t * freq;
        sv[tid] = sinf(a);
        cv[tid] = cosf(a);
    }
    __syncthreads();
    const unsigned short* rowp = qkvb + (size_t)tok * 2048;
#pragma unroll
    for (int e = tid; e < 1536; e += 256) {
        int u = e >> 6, d = e & 63;
        int col = (u < 16) ? (u * 64 + d) : (1024 + (u - 16) * 64 + d);
        int pcol = (d < 32) ? col + 32 : col - 32;
        float sgn = (d < 32) ? -1.f : 1.f;
        float o = bf2f(rowp[col]) * cv[d & 31] + sgn * bf2f(rowp[pcol]) * sv[d & 31];
        if (u < 16)
            qb[((size_t)(b * 16 + u) * 2048 + t) * 64 + d] = f2bf(o);
        else
            kb[((size_t)(b * 8 + (u - 16)) * 2048 + t) * 64 + d] = f2bf(o);
    }
}

// ---------------- V transpose: qkvb v-cols -> vt bf16 [b][h][64 d][2048 t] ----------------
__global__ __launch_bounds__(256) void vtrans_kernel(const unsigned short* __restrict__ qkvb,
                                                     unsigned short* __restrict__ vt) {
    __shared__ unsigned short tile[64][68];
    int t0 = blockIdx.x * 64, h = blockIdx.y, b = blockIdx.z;
    int tid = threadIdx.x;
    int d = tid & 63, tr = tid >> 6;
#pragma unroll
    for (int i = 0; i < 16; i++) {
        int t = tr + i * 4;
        tile[t][d] = qkvb[(size_t)(b * 2048 + t0 + t) * 2048 + 1536 + h * 64 + d];
    }
    __syncthreads();
    int tt = tid & 63, dr = tid >> 6;
#pragma unroll
    for (int i = 0; i < 16; i++) {
        int dd = dr + i * 4;
        vt[((size_t)(b * 8 + h) * 64 + dd) * 2048 + t0 + tt] = tile[tt][dd];
    }
}

// ---------------- flash attention, sliding window, soft cap ----------------
__global__ __launch_bounds__(256) void attn_kernel(const unsigned short* __restrict__ qb,
                                                   const unsigned short* __restrict__ kb,
                                                   const unsigned short* __restrict__ vt,
                                                   unsigned short* __restrict__ ctx) {
    __shared__ __align__(16) unsigned short P[4][16 * 32];
    const int tid = threadIdx.x, lane = tid & 63, w = tid >> 6;
    const int quad = lane >> 4, l15 = lane & 15;
    const int qt = blockIdx.x, H = blockIdx.y, b = blockIdx.z;
    const int hkv = H & 7;
    const int qw = qt * 64 + w * 16;

    const unsigned short* qbase = qb + ((size_t)(b * 16 + H) * 2048 + qw) * 64;
    short8 aq0 = *(const short8*)(qbase + (size_t)l15 * 64 + quad * 8);
    short8 aq1 = *(const short8*)(qbase + (size_t)l15 * 64 + 32 + quad * 8);

    const unsigned short* kbase = kb + (size_t)(b * 8 + hkv) * 2048 * 64;
    const unsigned short* vbase = vt + (size_t)(b * 8 + hkv) * 64 * 2048;

    f32x4 O[4];
#pragma unroll
    for (int i = 0; i < 4; i++) O[i] = f32x4{0.f, 0.f, 0.f, 0.f};
    float mrow[4], lrow[4];
#pragma unroll
    for (int r = 0; r < 4; r++) { mrow[r] = -1e30f; lrow[r] = 0.f; }

    int kstart = qw - 511;
    if (kstart < 0) kstart = 0;
    kstart &= ~31;
    unsigned short* Pw = P[w];

    for (int k0 = kstart; k0 <= qw + 15; k0 += 32) {
        f32x4 S[2];
#pragma unroll
        for (int c = 0; c < 2; c++) {
            const unsigned short* kp = kbase + (size_t)(k0 + c * 16 + l15) * 64 + quad * 8;
            short8 kf0 = *(const short8*)kp;
            short8 kf1 = *(const short8*)(kp + 32);
            f32x4 s = __builtin_amdgcn_mfma_f32_16x16x32_bf16(aq0, kf0, f32x4{0.f, 0.f, 0.f, 0.f}, 0, 0, 0);
            s = __builtin_amdgcn_mfma_f32_16x16x32_bf16(aq1, kf1, s, 0, 0, 0);
            S[c] = s;
        }
        float y[2][4];
#pragma unroll
        for (int c = 0; c < 2; c++)
#pragma unroll
            for (int r = 0; r < 4; r++) {
                int i = qw + quad * 4 + r;
                int j = k0 + c * 16 + l15;
                float x = S[c][r] * 0.125f;
                float tt = x * 0.02f;
                tt = fminf(8.f, fmaxf(-8.f, tt));
                float e = __expf(2.f * tt);
                float yv = 50.f * (e - 1.f) / (e + 1.f);
                y[c][r] = (j <= i && (i - j) < 512) ? yv : -__builtin_inff();
            }
        float p[2][4], alpha[4];
#pragma unroll
        for (int r = 0; r < 4; r++) {
            float v = fmaxf(y[0][r], y[1][r]);
#pragma unroll
            for (int mm = 8; mm; mm >>= 1) v = fmaxf(v, __shfl_xor(v, mm, 16));
            float mnew = fmaxf(mrow[r], v);
            alpha[r] = __expf(mrow[r] - mnew);
            float p0 = __expf(y[0][r] - mnew);
            float p1 = __expf(y[1][r] - mnew);
            p[0][r] = p0; p[1][r] = p1;
            float rs = p0 + p1;
#pragma unroll
            for (int mm = 8; mm; mm >>= 1) rs += __shfl_xor(rs, mm, 16);
            lrow[r] = lrow[r] * alpha[r] + rs;
            mrow[r] = mnew;
        }
#pragma unroll
        for (int c = 0; c < 2; c++)
#pragma unroll
            for (int r = 0; r < 4; r++)
                Pw[(quad * 4 + r) * 32 + c * 16 + l15] = f2bf(p[c][r]);
        asm volatile("s_waitcnt lgkmcnt(0)" ::: "memory");
        short8 pf = *(const short8*)&Pw[l15 * 32 + quad * 8];
#pragma unroll
        for (int ni = 0; ni < 4; ni++) {
            short8 vf = *(const short8*)(vbase + (size_t)(ni * 16 + l15) * 2048 + k0 + quad * 8);
            f32x4 o = O[ni];
#pragma unroll
            for (int r = 0; r < 4; r++) o[r] *= alpha[r];
            O[ni] = __builtin_amdgcn_mfma_f32_16x16x32_bf16(pf, vf, o, 0, 0, 0);
        }
        asm volatile("s_waitcnt lgkmcnt(0)" ::: "memory");
    }
#pragma unroll
    for (int r = 0; r < 4; r++) {
        float inv = 1.f / lrow[r];
        int i = qw + quad * 4 + r;
        size_t tok = (size_t)b * 2048 + i;
#pragma unroll
        for (int ni = 0; ni < 4; ni++)
            ctx[tok * 1024 + H * 64 + ni * 16 + l15] = f2bf(O[ni][r] * inv);
    }
}

// ---------------- kurtosis init ----------------
__global__ void kurt_init(float* dst, const float* ksum) { dst[0] = ksum[0]; }

// ---------------- launch ----------------
extern "C" void kernel_launch(void* const* d_in, const int* in_sizes, int n_in,
                              void* d_out, int out_size, void* d_ws, size_t ws_size,
                              hipStream_t stream) {
    const float* x = (const float*)d_in[0];
    const float* ksum = (const float*)d_in[1];
    const float* rms1_scale = (const float*)d_in[2];
    const float* q_kernel = (const float*)d_in[3];
    const float* k_kernel = (const float*)d_in[4];
    const float* v_kernel = (const float*)d_in[5];
    const float* out_kernel = (const float*)d_in[6];
    const float* rms2_scale = (const float*)d_in[7];
    const float* gate_kernel = (const float*)d_in[8];
    const float* up_kernel = (const float*)d_in[9];
    const float* down_kernel = (const float*)d_in[10];

    char* ws = (char*)d_ws;
    unsigned short* wqkv = (unsigned short*)(ws + OFF_WQKV);
    unsigned short* wout = (unsigned short*)(ws + OFF_WOUT);
    unsigned short* wgate = (unsigned short*)(ws + OFF_WGATE);
    unsigned short* wup = (unsigned short*)(ws + OFF_WUP);
    unsigned short* wdown = (unsigned short*)(ws + OFF_WDOWN);
    unsigned short* xn1 = (unsigned short*)(ws + OFF_XN1);
    unsigned short* qkvb = (unsigned short*)(ws + OFF_QKVB);
    float* p2 = (float*)(ws + OFF_P2);
    float* p4 = (float*)(ws + OFF_P4);
    unsigned short* qb = (unsigned short*)(ws + OFF_QB);
    unsigned short* kb = (unsigned short*)(ws + OFF_KB);
    unsigned short* vtb = (unsigned short*)(ws + OFF_VT);
    unsigned short* ctx = (unsigned short*)(ws + OFF_CTX);
    float* x2 = (float*)(ws + OFF_X2);
    unsigned short* xn2 = (unsigned short*)(ws + OFF_XN2);
    unsigned short* g = (unsigned short*)(ws + OFF_G);
    float* outx = (float*)d_out;
    float* outk = outx + (size_t)NTOK * C;

    // weight cast + transpose (W[K][N] -> Wt[N][K] bf16)
    transpose_cast<<<dim3(1024 / 32, 1024 / 32), 256, 0, stream>>>(q_kernel, wqkv, 1024, 1024);
    transpose_cast<<<dim3(512 / 32, 1024 / 32), 256, 0, stream>>>(k_kernel, wqkv + (size_t)1024 * 1024, 1024, 512);
    transpose_cast<<<dim3(512 / 32, 1024 / 32), 256, 0, stream>>>(v_kernel, wqkv + (size_t)1536 * 1024, 1024, 512);
    transpose_cast<<<dim3(1024 / 32, 1024 / 32), 256, 0, stream>>>(out_kernel, wout, 1024, 1024);
    transpose_cast<<<dim3(4096 / 32, 1024 / 32), 256, 0, stream>>>(gate_kernel, wgate, 1024, 4096);
    transpose_cast<<<dim3(4096 / 32, 1024 / 32), 256, 0, stream>>>(up_kernel, wup, 1024, 4096);
    transpose_cast<<<dim3(1024 / 32, 4096 / 32), 256, 0, stream>>>(down_kernel, wdown, 4096, 1024);

    // attention input norm
    rms_kernel<<<NTOK, 256, 0, stream>>>(x, rms1_scale, xn1);

    // QKV projection -> bf16 [4096][2048]
    gemm128<4><<<dim3(2048 / 128, NTOK / 128), 256, 0, stream>>>(
        xn1, wqkv, qkvb, 2048, 1024, 1024, 1024, 0, 0, 0);

    // RoPE + layout scatter, V transpose
    rope_kernel<<<NTOK, 256, 0, stream>>>(qkvb, qb, kb);
    vtrans_kernel<<<dim3(T / 64, NKV, Bsz), 256, 0, stream>>>(qkvb, vtb);

    // attention
    attn_kernel<<<dim3(T / 64, NH, Bsz), 256, 0, stream>>>(qb, kb, vtb, ctx);

    // out projection, split-K=2 -> partials, then fused residual+rms2
    gemm128<0><<<dim3(1024 / 128, NTOK / 128, 2), 256, 0, stream>>>(
        ctx, wout, p2, 1024, 512, 1024, 1024, 512, 512, (size_t)NTOK * 1024);
    reduce_out<<<NTOK, 256, 0, stream>>>(p2, x, rms2_scale, x2, xn2);

    // fused gate+up -> g = silu(gate)*up, bf16 [4096][4096]
    gateup_kernel<<<dim3(HID / 64, NTOK / 128), 256, 0, stream>>>(xn2, wgate, wup, g);

    // down projection, split-K=4 -> partials, then fused residual+kurtosis
    gemm128<0><<<dim3(1024 / 128, NTOK / 128, 4), 256, 0, stream>>>(
        g, wdown, p4, 1024, 1024, 4096, 4096, 1024, 1024, (size_t)NTOK * 1024);
    kurt_init<<<1, 1, 0, stream>>>(outk, ksum);
    reduce_down<<<NTOK, 256, 0, stream>>>(p4, x2, outx, outk);

    (void)in_sizes; (void)n_in; (void)out_size; (void)ws_size;
}